// Round 10
// baseline (208.961 us; speedup 1.0000x reference)
//
#include <hip/hip_runtime.h>

// ROI Align fp32, NCHW (B=2,C=256,H=W=200), 7x7 pooled, SAMPLE_NUM=2, mode=1.
//
// Round 10: fused producer/consumer overlap. Transpose (HBM-bound, ~20us) and
// gather (cache-fabric-bound ~10 TB/s, ~39us) use different HW units -> run
// them concurrently in ONE kernel:
//  - first NT=320 blocks (dynamic role claim, single padded atomic each)
//    transpose static stripe sets (role r: stripes r, r+NT, ...), posting
//    per-(batch, 64-row-group) progress after syncthreads+threadfence.
//  - all other blocks claim ROIs (sorted by batch,y_hi; ONE padded counter,
//    one claim per ROI - r9 lesson: no same-line claim storms) and spin with
//    s_sleep until their ROI's row groups are posted, then r8 gather body.
// Fallbacks: r8 two-kernel path (N<512), fp32 direct (tiny ws).

constexpr int C_TOT  = 256;
constexpr int H_FEAT = 200;
constexpr int W_FEAT = 200;
constexpr int HW     = H_FEAT * W_FEAT;
constexpr int S_TOT  = 49;
constexpr size_t FEATT_BYTES = (size_t)2 * HW * C_TOT * sizeof(unsigned short); // 40.96 MB
constexpr int NT      = 320;     // transposer blocks
constexpr int NSTRIPE = 2500;    // (b, 32-px spatial segment); 1250 per batch
constexpr int NBUCKET = 32;

// counter ints (each slot padded to 64 B = 16 ints) at qbase:
//   done[(b*4+g)*16]  b<2,g<4   (row groups of 64: sizes 400,400,400,50)
//   rolecnt = qbase[128], gcnt = qbase[144]
__device__ __forceinline__ int gsize(int g) { return g == 3 ? 50 : 400; }

__device__ __forceinline__ unsigned short bf16rne(float x) {
    unsigned int u = __float_as_uint(x);
    return (unsigned short)((u + 0x7fffu + ((u >> 16) & 1u)) >> 16);
}

__device__ __forceinline__ int roi_yhi(const float* r) {
    float y1c = r[2] * 0.25f;
    float y2c = (r[4] + 1.0f) * 0.25f;
    float ye  = y1c + fmaxf(y2c - y1c, 1.0f);
    return min(199, (int)fmaxf(ye, 0.0f) + 1);
}

// ---------------------------------------------------------------- binning
// perm[] = ROI indices bucketed by (batch, y_hi/16) -> batch-major, y asc.
// Also zeroes the fused kernel's counters.
__global__ __launch_bounds__(1024) void roi_bin_kernel(
    const float* __restrict__ rois, int* __restrict__ perm,
    int* __restrict__ qbase, int N)
{
    __shared__ int hist[NBUCKET];
    __shared__ int base[NBUCKET];
    __shared__ int cnt[NBUCKET];
    int t = threadIdx.x;

    if (t < NBUCKET) { hist[t] = 0; cnt[t] = 0; }
    if (t < 160) qbase[t] = 0;
    __syncthreads();

    int bucket = -1;
    if (t < N) {
        const float* r = rois + (size_t)t * 5;
        int b    = (int)r[0];
        int yh   = roi_yhi(r);
        bucket   = ((b & 1) << 4) | min(15, yh >> 4);
        atomicAdd(&hist[bucket], 1);
    }
    __syncthreads();
    if (t == 0) {
        int acc = 0;
        for (int i = 0; i < NBUCKET; ++i) { base[i] = acc; acc += hist[i]; }
    }
    __syncthreads();
    if (t < N) {
        int pos = base[bucket] + atomicAdd(&cnt[bucket], 1);
        perm[pos] = t;
    }
}

// ---------------------------------------------------------------- fused
__global__ __launch_bounds__(512) void roi_align_fused_kernel(
    const float* __restrict__ feat,
    unsigned short* __restrict__ featT,
    const float* __restrict__ rois,
    const int* __restrict__ perm,
    int* __restrict__ qbase,
    float* __restrict__ out,
    int N)
{
    __shared__ alignas(16) float smem[C_TOT * S_TOT];   // gather tile / ttile
    __shared__ int s_role, s_r;

    int tid  = threadIdx.x;
    int wave = tid >> 6;
    int lane = tid & 63;
    int half = lane >> 5;
    int li   = lane & 31;
    int xorsw = (li >> 2) & 7;

    if (tid == 0) s_role = atomicAdd(&qbase[128], 1);
    __syncthreads();
    int role = s_role;

    // ---------------- transpose phase (roles 0..NT-1) ----------------
    if (role < NT) {
        float (*tt)[32][33] = reinterpret_cast<float(*)[32][33]>(smem);
        int tx  = tid & 31;
        int tyw = (tid >> 5) & 7;
        int ti  = tid >> 8;                // 0..1
        for (int st = role; st < NSTRIPE; st += NT) {
            int b   = st >= 1250 ? 1 : 0;
            int sg  = st - b * 1250;
            int sp0 = sg * 32;
            const float* src = feat + (size_t)b * C_TOT * HW;
            unsigned short* dst = featT + (size_t)b * HW * C_TOT;
            #pragma unroll
            for (int ct = 0; ct < 4; ++ct) {
                int cb = (ct * 2 + ti) * 32;
                #pragma unroll
                for (int i = 0; i < 4; ++i) {
                    int r = tyw + i * 8;
                    tt[ti][r][tx] = src[(size_t)(cb + r) * HW + sp0 + tx];
                }
                __syncthreads();
                #pragma unroll
                for (int i = 0; i < 4; ++i) {
                    int r = tyw + i * 8;
                    dst[(size_t)(sp0 + r) * C_TOT + cb + tx] = bf16rne(tt[ti][tx][r]);
                }
                __syncthreads();
            }
            // stores drained by the barrier above; flush L2 and post progress
            if (tid == 0) {
                __threadfence();
                int g = sg < 400 ? 0 : sg < 800 ? 1 : sg < 1200 ? 2 : 3;
                atomicAdd(&qbase[(b * 4 + g) * 16], 1);
            }
        }
    }

    // ---------------- gather phase (everyone) ----------------
    while (true) {
        __syncthreads();                       // smem fully consumed
        if (tid == 0) s_r = atomicAdd(&qbase[144], 1);
        __syncthreads();
        int rk = s_r;
        if (rk >= N) break;
        int n = perm[rk];

        const float* r = rois + (size_t)n * 5;
        int   b  = (int)r[0];
        float x1 = r[1] * 0.25f;
        float y1 = r[2] * 0.25f;
        float x2 = (r[3] + 1.0f) * 0.25f;
        float y2 = (r[4] + 1.0f) * 0.25f;
        float bin_w = fmaxf(x2 - x1, 1.0f) * (1.0f / 7.0f);
        float bin_h = fmaxf(y2 - y1, 1.0f) * (1.0f / 7.0f);

        if (tid == 0) {
            int gw = min(3, roi_yhi(r) >> 6);
            for (int g = 0; g <= gw; ++g) {
                while (__hip_atomic_load(&qbase[(b * 4 + g) * 16],
                                         __ATOMIC_RELAXED,
                                         __HIP_MEMORY_SCOPE_AGENT) < gsize(g))
                    __builtin_amdgcn_s_sleep(16);
            }
        }
        __syncthreads();                       // rows ready for whole block

        const unsigned short* fb = featT + (size_t)b * HW * C_TOT + li * 8;

        for (int s = wave; s < S_TOT; s += 8) {
            int ph = s / 7;
            int pw = s - ph * 7;

            int   yoff[2][2], xoff[2][2];
            float wy[2][2], wx[2][2];
            #pragma unroll
            for (int i = 0; i < 2; ++i) {
                float gy  = (float)(2 * ph + i);
                float cy  = y1 + bin_h * ((gy + 0.5f) * 0.5f);
                bool  vy  = (cy >= -1.0f) && (cy <= (float)H_FEAT);
                float ccy = fminf(fmaxf(cy, 0.0f), (float)(H_FEAT - 1));
                int   ylo = (int)ccy;
                int   yhi = min(ylo + 1, H_FEAT - 1);
                float fy  = ccy - (float)ylo;
                yoff[i][0] = ylo * W_FEAT;
                yoff[i][1] = yhi * W_FEAT;
                wy[i][0] = vy ? (1.0f - fy) * 0.5f : 0.0f;
                wy[i][1] = vy ? fy * 0.5f          : 0.0f;

                float gx  = (float)(2 * pw + i);
                float cx  = x1 + bin_w * ((gx + 0.5f) * 0.5f);
                bool  vx  = (cx >= -1.0f) && (cx <= (float)W_FEAT);
                float ccx = fminf(fmaxf(cx, 0.0f), (float)(W_FEAT - 1));
                int   xlo = (int)ccx;
                int   xhi = min(xlo + 1, W_FEAT - 1);
                float fx  = ccx - (float)xlo;
                xoff[i][0] = xlo;
                xoff[i][1] = xhi;
                wx[i][0] = vx ? (1.0f - fx) * 0.5f : 0.0f;
                wx[i][1] = vx ? fx * 0.5f          : 0.0f;
            }

            float acc[8];
            #pragma unroll
            for (int j = 0; j < 8; ++j) acc[j] = 0.0f;

            #pragma unroll
            for (int iy = 0; iy < 2; ++iy)
            #pragma unroll
            for (int jy = 0; jy < 2; ++jy)
            #pragma unroll
            for (int ix = 0; ix < 2; ++ix) {
                int   pixA = yoff[iy][jy] + xoff[ix][0];
                int   pixB = yoff[iy][jy] + xoff[ix][1];
                float wA   = wy[iy][jy] * wx[ix][0];
                float wB   = wy[iy][jy] * wx[ix][1];
                int   pix  = half ? pixB : pixA;
                float w    = half ? wB   : wA;
                const uint4 v = *reinterpret_cast<const uint4*>(
                    fb + (size_t)pix * C_TOT);
                unsigned int u;
                u = v.x;
                acc[0] = fmaf(w, __uint_as_float(u << 16),         acc[0]);
                acc[1] = fmaf(w, __uint_as_float(u & 0xffff0000u), acc[1]);
                u = v.y;
                acc[2] = fmaf(w, __uint_as_float(u << 16),         acc[2]);
                acc[3] = fmaf(w, __uint_as_float(u & 0xffff0000u), acc[3]);
                u = v.z;
                acc[4] = fmaf(w, __uint_as_float(u << 16),         acc[4]);
                acc[5] = fmaf(w, __uint_as_float(u & 0xffff0000u), acc[5]);
                u = v.w;
                acc[6] = fmaf(w, __uint_as_float(u << 16),         acc[6]);
                acc[7] = fmaf(w, __uint_as_float(u & 0xffff0000u), acc[7]);
            }

            #pragma unroll
            for (int j = 0; j < 8; ++j) {
                float sum = acc[j] + __shfl_xor(acc[j], 32);
                if (half == 0) {
                    int slot_ch = li * 8 + (j ^ xorsw);
                    smem[slot_ch * S_TOT + s] = sum;
                }
            }
        }
        __syncthreads();

        float4* o4 = reinterpret_cast<float4*>(out + (size_t)n * (C_TOT * S_TOT));
        constexpr int Q4 = C_TOT * S_TOT / 4;   // 3136
        for (int q4 = tid; q4 < Q4; q4 += 512) {
            int qq0 = q4 * 4;
            float4 val;
            float* vp = reinterpret_cast<float*>(&val);
            #pragma unroll
            for (int e = 0; e < 4; ++e) {
                int qq = qq0 + e;
                int ch = qq / S_TOT;
                int ss = qq - ch * S_TOT;
                int slot_ch = (ch & ~7) | ((ch & 7) ^ ((ch >> 5) & 7));
                vp[e] = smem[slot_ch * S_TOT + ss];
            }
            o4[q4] = val;
        }
    }
}

// ---------------------------------------------------------------- r8 fallback kernels
__global__ __launch_bounds__(256) void nchw_to_nhwc_bf16_kernel(
    const float* __restrict__ feat, unsigned short* __restrict__ featT)
{
    __shared__ float tile[32][33];
    int tx = threadIdx.x, ty = threadIdx.y;
    int s0 = blockIdx.x * 32, c0 = blockIdx.y * 32, b = blockIdx.z;
    const float* src = feat + ((size_t)b * C_TOT) * HW;
    #pragma unroll
    for (int i = 0; i < 4; ++i) {
        int r = ty + i * 8;
        tile[r][tx] = src[(size_t)(c0 + r) * HW + (s0 + tx)];
    }
    __syncthreads();
    unsigned short* dst = featT + ((size_t)b * HW) * C_TOT;
    #pragma unroll
    for (int i = 0; i < 4; ++i) {
        int r = ty + i * 8;
        dst[(size_t)(s0 + r) * C_TOT + (c0 + tx)] = bf16rne(tile[tx][r]);
    }
}

__global__ __launch_bounds__(512) void roi_align_nhwc_kernel(
    const unsigned short* __restrict__ featT,
    const float* __restrict__ rois,
    float* __restrict__ out, int N)
{
    __shared__ alignas(16) float tile[C_TOT * S_TOT];
    int n = blockIdx.x;
    int tid = threadIdx.x, wave = tid >> 6, lane = tid & 63;
    int half = lane >> 5, li = lane & 31, xorsw = (li >> 2) & 7;

    const float* r = rois + (size_t)n * 5;
    int   b  = (int)r[0];
    float x1 = r[1] * 0.25f, y1 = r[2] * 0.25f;
    float x2 = (r[3] + 1.0f) * 0.25f, y2 = (r[4] + 1.0f) * 0.25f;
    float bin_w = fmaxf(x2 - x1, 1.0f) * (1.0f / 7.0f);
    float bin_h = fmaxf(y2 - y1, 1.0f) * (1.0f / 7.0f);
    const unsigned short* fb = featT + (size_t)b * HW * C_TOT + li * 8;

    for (int s = wave; s < S_TOT; s += 8) {
        int ph = s / 7, pw = s - ph * 7;
        int yoff[2][2], xoff[2][2];
        float wy[2][2], wx[2][2];
        #pragma unroll
        for (int i = 0; i < 2; ++i) {
            float gy = (float)(2 * ph + i);
            float cy = y1 + bin_h * ((gy + 0.5f) * 0.5f);
            bool  vy = (cy >= -1.0f) && (cy <= (float)H_FEAT);
            float ccy = fminf(fmaxf(cy, 0.0f), (float)(H_FEAT - 1));
            int ylo = (int)ccy, yhi = min(ylo + 1, H_FEAT - 1);
            float fy = ccy - (float)ylo;
            yoff[i][0] = ylo * W_FEAT; yoff[i][1] = yhi * W_FEAT;
            wy[i][0] = vy ? (1.0f - fy) * 0.5f : 0.0f;
            wy[i][1] = vy ? fy * 0.5f          : 0.0f;
            float gx = (float)(2 * pw + i);
            float cx = x1 + bin_w * ((gx + 0.5f) * 0.5f);
            bool  vx = (cx >= -1.0f) && (cx <= (float)W_FEAT);
            float ccx = fminf(fmaxf(cx, 0.0f), (float)(W_FEAT - 1));
            int xlo = (int)ccx, xhi = min(xlo + 1, W_FEAT - 1);
            float fx = ccx - (float)xlo;
            xoff[i][0] = xlo; xoff[i][1] = xhi;
            wx[i][0] = vx ? (1.0f - fx) * 0.5f : 0.0f;
            wx[i][1] = vx ? fx * 0.5f          : 0.0f;
        }
        float acc[8];
        #pragma unroll
        for (int j = 0; j < 8; ++j) acc[j] = 0.0f;
        #pragma unroll
        for (int iy = 0; iy < 2; ++iy)
        #pragma unroll
        for (int jy = 0; jy < 2; ++jy)
        #pragma unroll
        for (int ix = 0; ix < 2; ++ix) {
            int pixA = yoff[iy][jy] + xoff[ix][0];
            int pixB = yoff[iy][jy] + xoff[ix][1];
            float wA = wy[iy][jy] * wx[ix][0];
            float wB = wy[iy][jy] * wx[ix][1];
            int pix = half ? pixB : pixA;
            float w = half ? wB : wA;
            const uint4 v = *reinterpret_cast<const uint4*>(fb + (size_t)pix * C_TOT);
            unsigned int u;
            u = v.x; acc[0] = fmaf(w, __uint_as_float(u << 16), acc[0]);
                     acc[1] = fmaf(w, __uint_as_float(u & 0xffff0000u), acc[1]);
            u = v.y; acc[2] = fmaf(w, __uint_as_float(u << 16), acc[2]);
                     acc[3] = fmaf(w, __uint_as_float(u & 0xffff0000u), acc[3]);
            u = v.z; acc[4] = fmaf(w, __uint_as_float(u << 16), acc[4]);
                     acc[5] = fmaf(w, __uint_as_float(u & 0xffff0000u), acc[5]);
            u = v.w; acc[6] = fmaf(w, __uint_as_float(u << 16), acc[6]);
                     acc[7] = fmaf(w, __uint_as_float(u & 0xffff0000u), acc[7]);
        }
        #pragma unroll
        for (int j = 0; j < 8; ++j) {
            float sum = acc[j] + __shfl_xor(acc[j], 32);
            if (half == 0) tile[(li * 8 + (j ^ xorsw)) * S_TOT + s] = sum;
        }
    }
    __syncthreads();
    float4* o4 = reinterpret_cast<float4*>(out + (size_t)n * (C_TOT * S_TOT));
    constexpr int Q4 = C_TOT * S_TOT / 4;
    for (int q4 = tid; q4 < Q4; q4 += 512) {
        int qq0 = q4 * 4;
        float4 val;
        float* vp = reinterpret_cast<float*>(&val);
        #pragma unroll
        for (int e = 0; e < 4; ++e) {
            int qq = qq0 + e;
            int ch = qq / S_TOT, ss = qq - ch * S_TOT;
            int slot_ch = (ch & ~7) | ((ch & 7) ^ ((ch >> 5) & 7));
            vp[e] = tile[slot_ch * S_TOT + ss];
        }
        o4[q4] = val;
    }
}

// ---------------------------------------------------------------- fp32 fallback
constexpr int CPT = 4;
constexpr int CG  = C_TOT / CPT;

__global__ __launch_bounds__(256) void roi_align_direct_kernel(
    const float* __restrict__ feat, const float* __restrict__ rois,
    float* __restrict__ out, int N)
{
    int t = blockIdx.x * 256 + threadIdx.x;
    int total = N * CG * S_TOT;
    if (t >= total) return;
    int s = t % S_TOT, rem = t / S_TOT, c0 = rem % CG, n = rem / CG;
    int ph = s / 7, pw = s - ph * 7;
    const float* r = rois + (size_t)n * 5;
    int   b  = (int)r[0];
    float x1 = r[1] * 0.25f, y1 = r[2] * 0.25f;
    float x2 = (r[3] + 1.0f) * 0.25f, y2 = (r[4] + 1.0f) * 0.25f;
    float bin_w = fmaxf(x2 - x1, 1.0f) * (1.0f / 7.0f);
    float bin_h = fmaxf(y2 - y1, 1.0f) * (1.0f / 7.0f);
    int roff[2][2], coff[2][2];
    float wy[2][2], wx[2][2];
    #pragma unroll
    for (int i = 0; i < 2; ++i) {
        float gy = (float)(2 * ph + i);
        float cy = y1 + bin_h * ((gy + 0.5f) * 0.5f);
        bool  vy = (cy >= -1.0f) && (cy <= (float)H_FEAT);
        float ccy = fminf(fmaxf(cy, 0.0f), (float)(H_FEAT - 1));
        int ylo = (int)ccy, yhi = min(ylo + 1, H_FEAT - 1);
        float fy = ccy - (float)ylo;
        roff[i][0] = ylo * W_FEAT; roff[i][1] = yhi * W_FEAT;
        wy[i][0] = vy ? (1.0f - fy) : 0.0f;
        wy[i][1] = vy ? fy          : 0.0f;
        float gx = (float)(2 * pw + i);
        float cx = x1 + bin_w * ((gx + 0.5f) * 0.5f);
        bool  vx = (cx >= -1.0f) && (cx <= (float)W_FEAT);
        float ccx = fminf(fmaxf(cx, 0.0f), (float)(W_FEAT - 1));
        int xlo = (int)ccx, xhi = min(xlo + 1, W_FEAT - 1);
        float fx = ccx - (float)xlo;
        coff[i][0] = xlo; coff[i][1] = xhi;
        wx[i][0] = vx ? (1.0f - fx) : 0.0f;
        wx[i][1] = vx ? fx          : 0.0f;
    }
    float w16[16]; int o16[16];
    #pragma unroll
    for (int iy = 0; iy < 2; ++iy)
    #pragma unroll
    for (int ix = 0; ix < 2; ++ix)
    #pragma unroll
    for (int jy = 0; jy < 2; ++jy)
    #pragma unroll
    for (int jx = 0; jx < 2; ++jx) {
        int idx = ((iy * 2 + ix) * 2 + jy) * 2 + jx;
        w16[idx] = wy[iy][jy] * wx[ix][jx];
        o16[idx] = roff[iy][jy] + coff[ix][jx];
    }
    size_t base  = ((size_t)b * C_TOT + c0) * HW;
    size_t obase = (size_t)n * (C_TOT * S_TOT) + (size_t)c0 * S_TOT + s;
    #pragma unroll
    for (int k = 0; k < CPT; ++k) {
        const float* f = feat + base + (size_t)k * CG * HW;
        float acc = 0.0f;
        #pragma unroll
        for (int j = 0; j < 16; ++j)
            acc = fmaf(w16[j], f[o16[j]], acc);
        out[obase + (size_t)k * (CG * S_TOT)] = acc * 0.25f;
    }
}

extern "C" void kernel_launch(void* const* d_in, const int* in_sizes, int n_in,
                              void* d_out, int out_size, void* d_ws, size_t ws_size,
                              hipStream_t stream) {
    const float* feat = (const float*)d_in[0];
    const float* rois = (const float*)d_in[1];
    float* out = (float*)d_out;
    int N = in_sizes[1] / 5;

    size_t need = FEATT_BYTES + 4096 + 1024;
    if (ws_size >= need && N >= 512 && N <= 1024) {
        unsigned short* featT = (unsigned short*)d_ws;
        int* perm  = (int*)((char*)d_ws + FEATT_BYTES);
        int* qbase = (int*)((char*)d_ws + FEATT_BYTES + 4096);
        roi_bin_kernel<<<1, 1024, 0, stream>>>(rois, perm, qbase, N);
        roi_align_fused_kernel<<<N, 512, 0, stream>>>(
            feat, featT, rois, perm, qbase, out, N);
    } else if (ws_size >= need && N <= 1024) {
        unsigned short* featT = (unsigned short*)d_ws;
        dim3 tgrid(HW / 32, C_TOT / 32, 2);
        dim3 tblk(32, 8);
        nchw_to_nhwc_bf16_kernel<<<tgrid, tblk, 0, stream>>>(feat, featT);
        roi_align_nhwc_kernel<<<N, 512, 0, stream>>>(featT, rois, out, N);
    } else {
        int total  = N * CG * S_TOT;
        int blocks = (total + 255) / 256;
        roi_align_direct_kernel<<<blocks, 256, 0, stream>>>(feat, rois, out, N);
    }
}

// Round 11
// 61.511 us; speedup vs baseline: 3.3971x; 3.3971x over previous
//
#include <hip/hip_runtime.h>
#include <hip/hip_bf16.h>

// ROI Align fp32, NCHW input (B=2, C=256, H=W=200), pooled 7x7, SAMPLE_NUM=2,
// SPATIAL_SCALE=0.25, ROI_END_MODE=1.
//
// Round 11: REVERT to the round-8 configuration (measured optimum, 60.8 us).
// r9 (XCD work queues) and r10 (fused producer/consumer overlap) both
// regressed: contended same-line device atomics (r9) and per-post
// cross-XCD L2 writebacks (r10) are structurally expensive on CDNA4.
// Final pipeline:
//   Phase 0: roi_bin_kernel -> perm[] (batch x 4x4 spatial buckets, ~1us)
//   Phase 1: NCHW fp32 -> NHWC bf16 transpose into d_ws (41 MB; 123 MB HBM
//            traffic @ ~6.2 TB/s = at the achievable HBM ceiling, ~20us)
//   Phase 2: gather, one block (512 thr) per ROI via chunked XCD mapping;
//            paired corner loads (2 pixels / 1 KB wave-load), bf16->fp32
//            accumulate, shfl merge, swizzled LDS staging, linear float4
//            stores (~39us @ ~10.3 TB/s scattered-line L3/fabric service).

constexpr int C_TOT  = 256;
constexpr int H_FEAT = 200;
constexpr int W_FEAT = 200;
constexpr int HW     = H_FEAT * W_FEAT;
constexpr int S_TOT  = 49;             // 7*7 pooled cells
constexpr size_t FEATT_BYTES = (size_t)2 * HW * C_TOT * sizeof(unsigned short); // 40.96 MB
constexpr int NXCD = 8;
constexpr int NBUCKET = 32;            // b(1) x qy(2) x qx(2) bits

// ---------------------------------------------------------------- ROI binning
__global__ __launch_bounds__(1024) void roi_bin_kernel(
    const float* __restrict__ rois, int* __restrict__ perm, int N)
{
    __shared__ int hist[NBUCKET];
    __shared__ int base[NBUCKET];
    __shared__ int cnt[NBUCKET];
    int t = threadIdx.x;

    if (t < NBUCKET) { hist[t] = 0; cnt[t] = 0; }
    __syncthreads();

    int bucket = -1;
    if (t < N) {
        const float* r = rois + (size_t)t * 5;
        int   b  = (int)r[0];
        float cx = (r[1] + r[3]) * 0.5f * 0.25f;   // feature-space center
        float cy = (r[2] + r[4]) * 0.5f * 0.25f;
        int qx = min(max((int)(cx * (4.0f / 200.0f)), 0), 3);
        int qy = min(max((int)(cy * (4.0f / 200.0f)), 0), 3);
        bucket = ((b & 1) << 4) | (qy << 2) | qx;
        atomicAdd(&hist[bucket], 1);
    }
    __syncthreads();

    if (t == 0) {
        int acc = 0;
        for (int i = 0; i < NBUCKET; ++i) { base[i] = acc; acc += hist[i]; }
    }
    __syncthreads();

    if (t < N) {
        int pos = base[bucket] + atomicAdd(&cnt[bucket], 1);
        perm[pos] = t;
    }
}

// ---------------------------------------------------------------- transpose
// feat[b][c][s] (fp32) -> featT[b][s][c] (bf16, RNE).
__global__ __launch_bounds__(256) void nchw_to_nhwc_bf16_kernel(
    const float* __restrict__ feat,
    unsigned short* __restrict__ featT)
{
    __shared__ float tile[32][33];
    int tx = threadIdx.x;        // 0..31
    int ty = threadIdx.y;        // 0..7
    int s0 = blockIdx.x * 32;
    int c0 = blockIdx.y * 32;
    int b  = blockIdx.z;

    const float* src = feat + ((size_t)b * C_TOT) * HW;
    #pragma unroll
    for (int i = 0; i < 4; ++i) {
        int r = ty + i * 8;      // channel within tile
        tile[r][tx] = src[(size_t)(c0 + r) * HW + (s0 + tx)];
    }
    __syncthreads();
    unsigned short* dst = featT + ((size_t)b * HW) * C_TOT;
    #pragma unroll
    for (int i = 0; i < 4; ++i) {
        int r = ty + i * 8;      // spatial within tile
        float x = tile[tx][r];
        unsigned int u = __float_as_uint(x);
        unsigned int rb = (u + 0x7fffu + ((u >> 16) & 1u)) >> 16;   // RNE
        dst[(size_t)(s0 + r) * C_TOT + (c0 + tx)] = (unsigned short)rb;
    }
}

// ---------------------------------------------------------------- gather
__global__ __launch_bounds__(512) void roi_align_nhwc_kernel(
    const unsigned short* __restrict__ featT,
    const float* __restrict__ rois,
    const int* __restrict__ perm,
    float* __restrict__ out,
    int N, int use_perm)
{
    // tile[slot_ch][s]; slot_ch = (ch & ~7) | ((ch&7) ^ ((ch>>5)&7))
    __shared__ alignas(16) float tile[C_TOT * S_TOT];

    int n;
    if (use_perm) {
        // chunked XCD transform: XCD x gets sorted ranks [x*chunk, (x+1)*chunk)
        int chunk = (N + NXCD - 1) / NXCD;
        int rank  = (blockIdx.x & (NXCD - 1)) * chunk + (blockIdx.x >> 3);
        if (rank >= N) rank = blockIdx.x;
        n = perm[rank];
    } else {
        n = blockIdx.x;
    }

    int tid  = threadIdx.x;
    int wave = tid >> 6;         // 0..7
    int lane = tid & 63;
    int half = lane >> 5;        // 0: pixel A (xlo corner), 1: pixel B (xhi)
    int li   = lane & 31;        // channel-group within half: ch 8*li..8*li+7

    const float* r = rois + (size_t)n * 5;
    int   b  = (int)r[0];
    float x1 = r[1] * 0.25f;
    float y1 = r[2] * 0.25f;
    float x2 = (r[3] + 1.0f) * 0.25f;
    float y2 = (r[4] + 1.0f) * 0.25f;
    float bin_w = fmaxf(x2 - x1, 1.0f) * (1.0f / 7.0f);
    float bin_h = fmaxf(y2 - y1, 1.0f) * (1.0f / 7.0f);

    const unsigned short* fb = featT + (size_t)b * HW * C_TOT + li * 8;
    int xorsw = (li >> 2) & 7;

    for (int s = wave; s < S_TOT; s += 8) {
        int ph = s / 7;
        int pw = s - ph * 7;

        int   yoff[2][2];
        int   xoff[2][2];
        float wy[2][2], wx[2][2];
        #pragma unroll
        for (int i = 0; i < 2; ++i) {
            float gy  = (float)(2 * ph + i);
            float cy  = y1 + bin_h * ((gy + 0.5f) * 0.5f);
            bool  vy  = (cy >= -1.0f) && (cy <= (float)H_FEAT);
            float ccy = fminf(fmaxf(cy, 0.0f), (float)(H_FEAT - 1));
            int   ylo = (int)ccy;
            int   yhi = min(ylo + 1, H_FEAT - 1);
            float fy  = ccy - (float)ylo;
            yoff[i][0] = ylo * W_FEAT;
            yoff[i][1] = yhi * W_FEAT;
            // fold 0.5 per axis -> product carries the 0.25 sample-average
            wy[i][0] = vy ? (1.0f - fy) * 0.5f : 0.0f;
            wy[i][1] = vy ? fy * 0.5f          : 0.0f;

            float gx  = (float)(2 * pw + i);
            float cx  = x1 + bin_w * ((gx + 0.5f) * 0.5f);
            bool  vx  = (cx >= -1.0f) && (cx <= (float)W_FEAT);
            float ccx = fminf(fmaxf(cx, 0.0f), (float)(W_FEAT - 1));
            int   xlo = (int)ccx;
            int   xhi = min(xlo + 1, W_FEAT - 1);
            float fx  = ccx - (float)xlo;
            xoff[i][0] = xlo;
            xoff[i][1] = xhi;
            wx[i][0] = vx ? (1.0f - fx) * 0.5f : 0.0f;
            wx[i][1] = vx ? fx * 0.5f          : 0.0f;
        }

        float acc[8];
        #pragma unroll
        for (int j = 0; j < 8; ++j) acc[j] = 0.0f;

        // 8 paired wave-loads: half 0 reads the xlo corner, half 1 the xhi.
        #pragma unroll
        for (int iy = 0; iy < 2; ++iy)
        #pragma unroll
        for (int jy = 0; jy < 2; ++jy)
        #pragma unroll
        for (int ix = 0; ix < 2; ++ix) {
            int   pixA = yoff[iy][jy] + xoff[ix][0];
            int   pixB = yoff[iy][jy] + xoff[ix][1];
            float wA   = wy[iy][jy] * wx[ix][0];
            float wB   = wy[iy][jy] * wx[ix][1];
            int   pix  = half ? pixB : pixA;
            float w    = half ? wB   : wA;
            const uint4 v = *reinterpret_cast<const uint4*>(
                fb + (size_t)pix * C_TOT);
            unsigned int u;
            u = v.x;
            acc[0] = fmaf(w, __uint_as_float(u << 16),          acc[0]);
            acc[1] = fmaf(w, __uint_as_float(u & 0xffff0000u),  acc[1]);
            u = v.y;
            acc[2] = fmaf(w, __uint_as_float(u << 16),          acc[2]);
            acc[3] = fmaf(w, __uint_as_float(u & 0xffff0000u),  acc[3]);
            u = v.z;
            acc[4] = fmaf(w, __uint_as_float(u << 16),          acc[4]);
            acc[5] = fmaf(w, __uint_as_float(u & 0xffff0000u),  acc[5]);
            u = v.w;
            acc[6] = fmaf(w, __uint_as_float(u << 16),          acc[6]);
            acc[7] = fmaf(w, __uint_as_float(u & 0xffff0000u),  acc[7]);
        }

        // merge the two corner-halves; lanes 0-31 hold the full sum for
        // channels 8*li .. 8*li+7 and write LDS with a conflict-free swizzle.
        #pragma unroll
        for (int j = 0; j < 8; ++j) {
            float sum = acc[j] + __shfl_xor(acc[j], 32);
            if (half == 0) {
                int slot_ch = li * 8 + (j ^ xorsw);
                tile[slot_ch * S_TOT + s] = sum;
            }
        }
    }
    __syncthreads();

    // Copy-out: invert the channel swizzle, contiguous float4 global stores.
    float4* o4 = reinterpret_cast<float4*>(out + (size_t)n * (C_TOT * S_TOT));
    constexpr int Q4 = C_TOT * S_TOT / 4;   // 3136
    for (int q4 = tid; q4 < Q4; q4 += 512) {
        int q = q4 * 4;
        float4 val;
        float* vp = reinterpret_cast<float*>(&val);
        #pragma unroll
        for (int e = 0; e < 4; ++e) {
            int qq = q + e;
            int ch = qq / S_TOT;
            int ss = qq - ch * S_TOT;
            int slot_ch = (ch & ~7) | ((ch & 7) ^ ((ch >> 5) & 7));
            vp[e] = tile[slot_ch * S_TOT + ss];
        }
        o4[q4] = val;
    }
}

// ---------------------------------------------------------------- fp32 fallback
constexpr int CPT = 4;
constexpr int CG  = C_TOT / CPT;

__global__ __launch_bounds__(256) void roi_align_direct_kernel(
    const float* __restrict__ feat,
    const float* __restrict__ rois,
    float* __restrict__ out,
    int N)
{
    int t = blockIdx.x * 256 + threadIdx.x;
    int total = N * CG * S_TOT;
    if (t >= total) return;

    int s   = t % S_TOT;
    int rem = t / S_TOT;
    int c0  = rem % CG;
    int n   = rem / CG;
    int ph  = s / 7;
    int pw  = s - ph * 7;

    const float* r = rois + (size_t)n * 5;
    int   b  = (int)r[0];
    float x1 = r[1] * 0.25f;
    float y1 = r[2] * 0.25f;
    float x2 = (r[3] + 1.0f) * 0.25f;
    float y2 = (r[4] + 1.0f) * 0.25f;
    float bin_w = fmaxf(x2 - x1, 1.0f) * (1.0f / 7.0f);
    float bin_h = fmaxf(y2 - y1, 1.0f) * (1.0f / 7.0f);

    int   roff[2][2], coff[2][2];
    float wy[2][2], wx[2][2];
    #pragma unroll
    for (int i = 0; i < 2; ++i) {
        float gy  = (float)(2 * ph + i);
        float cy  = y1 + bin_h * ((gy + 0.5f) * 0.5f);
        bool  vy  = (cy >= -1.0f) && (cy <= (float)H_FEAT);
        float ccy = fminf(fmaxf(cy, 0.0f), (float)(H_FEAT - 1));
        int   ylo = (int)ccy;
        int   yhi = min(ylo + 1, H_FEAT - 1);
        float fy  = ccy - (float)ylo;
        roff[i][0] = ylo * W_FEAT;
        roff[i][1] = yhi * W_FEAT;
        wy[i][0] = vy ? (1.0f - fy) : 0.0f;
        wy[i][1] = vy ? fy          : 0.0f;

        float gx  = (float)(2 * pw + i);
        float cx  = x1 + bin_w * ((gx + 0.5f) * 0.5f);
        bool  vx  = (cx >= -1.0f) && (cx <= (float)W_FEAT);
        float ccx = fminf(fmaxf(cx, 0.0f), (float)(W_FEAT - 1));
        int   xlo = (int)ccx;
        int   xhi = min(xlo + 1, W_FEAT - 1);
        float fx  = ccx - (float)xlo;
        coff[i][0] = xlo;
        coff[i][1] = xhi;
        wx[i][0] = vx ? (1.0f - fx) : 0.0f;
        wx[i][1] = vx ? fx          : 0.0f;
    }

    float w16[16];
    int   o16[16];
    #pragma unroll
    for (int iy = 0; iy < 2; ++iy)
    #pragma unroll
    for (int ix = 0; ix < 2; ++ix)
    #pragma unroll
    for (int jy = 0; jy < 2; ++jy)
    #pragma unroll
    for (int jx = 0; jx < 2; ++jx) {
        int idx = ((iy * 2 + ix) * 2 + jy) * 2 + jx;
        w16[idx] = wy[iy][jy] * wx[ix][jx];
        o16[idx] = roff[iy][jy] + coff[ix][jx];
    }

    size_t base  = ((size_t)b * C_TOT + c0) * HW;
    size_t obase = (size_t)n * (C_TOT * S_TOT) + (size_t)c0 * S_TOT + s;

    #pragma unroll
    for (int k = 0; k < CPT; ++k) {
        const float* f = feat + base + (size_t)k * CG * HW;
        float acc = 0.0f;
        #pragma unroll
        for (int j = 0; j < 16; ++j)
            acc = fmaf(w16[j], f[o16[j]], acc);
        out[obase + (size_t)k * (CG * S_TOT)] = acc * 0.25f;
    }
}

extern "C" void kernel_launch(void* const* d_in, const int* in_sizes, int n_in,
                              void* d_out, int out_size, void* d_ws, size_t ws_size,
                              hipStream_t stream) {
    const float* feat = (const float*)d_in[0];
    const float* rois = (const float*)d_in[1];
    float* out = (float*)d_out;
    int N = in_sizes[1] / 5;

    size_t need = FEATT_BYTES + 4096;
    if (ws_size >= need) {
        unsigned short* featT = (unsigned short*)d_ws;
        int* perm = (int*)((char*)d_ws + FEATT_BYTES);
        int use_perm = (N <= 1024) ? 1 : 0;
        if (use_perm)
            roi_bin_kernel<<<1, 1024, 0, stream>>>(rois, perm, N);
        dim3 tgrid(HW / 32, C_TOT / 32, 2);
        dim3 tblk(32, 8);
        nchw_to_nhwc_bf16_kernel<<<tgrid, tblk, 0, stream>>>(feat, featT);
        roi_align_nhwc_kernel<<<N, 512, 0, stream>>>(featT, rois, perm, out, N, use_perm);
    } else {
        int total  = N * CG * S_TOT;
        int blocks = (total + 255) / 256;
        roi_align_direct_kernel<<<blocks, 256, 0, stream>>>(feat, rois, out, N);
    }
}